// Round 10
// baseline (137.829 us; speedup 1.0000x reference)
//
#include <hip/hip_runtime.h>

// x (4096, 2, 1024) fp32.  P_i = x[i,0,:], A_j = x[i,1,:]
// out[0] = 1.0 exactly; out[1] = prec1 = 100*mean(argmax_j sim[i,j] == i)
// R22: seven schedule variants (R12,R15,R17-R21) all sit at 22-27% MfmaUtil
// -> scheduling falsified as lever. Resource analysis: 6 ds_read per 8 MFMA
// = 768B LDS-read/MFMA -> per CU-phase LDS 578cyc > MFMA 258cyc (LDS-path
// bound + short 8-MFMA chains). Fix: 128x128 per wave (4 waves, 256 thr,
// same 256x256 block tile, same frag map): 8 reads -> 16 MFMA = 512B/MFMA;
// per CU-phase LDS 385cyc < MFMA 516cyc (MFMA-bound on paper). acc[4][4] =
// 256 VGPR -> 1 wave/SIMD (launch_bounds(256,1)); lost TLP compensated by
// R17 one-barrier/tile skeleton + R20 two-set read pipeline (reads of phase
// k+1 issue under phase k's 512cyc MFMA pipe occupancy). K-accumulation
// order unchanged -> bitwise-identical C -> absmax 0 preserved.
// Frag-order map (R4/R9/R11-verified): block fb region = 64KB at fb*65536;
// byte = kh*1024 + lane*16 -> (row = fb*32 + (lane&31), k = kh*16+(lane>>5)*8..+8).

#define NROWS 4096
#define DDIM  1024
#define XSTR  2048

typedef unsigned int u32;
typedef unsigned long long u64;
typedef __attribute__((ext_vector_type(8))) short bf16x8;
typedef __attribute__((ext_vector_type(8))) unsigned short u16x8;
typedef __attribute__((ext_vector_type(16))) float f32x16;

__device__ __forceinline__ unsigned int fkey(float f) {
    unsigned int u = __float_as_uint(f);
    return (u & 0x80000000u) ? ~u : (u | 0x80000000u);
}

__device__ __forceinline__ u64 shfl_xor_u64(u64 v, int m) {
    unsigned int lo = (unsigned int)v;
    unsigned int hi = (unsigned int)(v >> 32);
    lo = __shfl_xor(lo, m, 64);
    hi = __shfl_xor(hi, m, 64);
    return ((u64)hi << 32) | lo;
}

__device__ __forceinline__ unsigned short f2bf(float f) {
    unsigned u = __float_as_uint(f);
    return (unsigned short)((u + 0x7FFFu + ((u >> 16) & 1u)) >> 16);
}

// Workspace layout (bytes):
#define PF_OFF   0u
#define AF_OFF   8388608u
#define INV_OFF  16777216u
#define PCK_OFF  16793600u
#define DONE_OFF 16826368u
#define WS_NEED  16826432u

// ---- prep: norms (one wave per row, coalesced) + zero packed/done ----
__global__ __launch_bounds__(256) void norms2_kernel(const float* __restrict__ x,
                                                     float* __restrict__ inv_an,
                                                     u64* __restrict__ packed,
                                                     unsigned int* __restrict__ done) {
    int gid  = blockIdx.x * 256 + threadIdx.x;
    int j    = gid >> 6;
    int lane = threadIdx.x & 63;
    if (gid < NROWS) packed[gid] = 0ULL;
    if (gid == 0) *done = 0u;
    const float4* a = (const float4*)(x + (size_t)j * XSTR + DDIM);
    float s = 0.0f;
#pragma unroll
    for (int i = 0; i < 4; ++i) {
        float4 v = a[lane + i * 64];
        s += v.x * v.x + v.y * v.y + v.z * v.z + v.w * v.w;
    }
#pragma unroll
    for (int off = 32; off > 0; off >>= 1) s += __shfl_down(s, off, 64);
    if (lane == 0) inv_an[j] = 1.0f / sqrtf(s);
}

// ---- prep: fp32 -> bf16 fragment conversion, one thread per 16B chunk ----
__global__ __launch_bounds__(256) void conv_kernel(const float* __restrict__ x,
                                                   unsigned short* __restrict__ Pf,
                                                   unsigned short* __restrict__ Af) {
    const int cid  = blockIdx.x * 256 + threadIdx.x;
    const int lane = cid & 63;
    const int kh   = (cid >> 6) & 63;
    const int fb   = cid >> 12;
    const int row  = fb * 32 + (lane & 31);
    const int col  = kh * 16 + (lane >> 5) * 8;

    const float* px = x + (size_t)row * XSTR + col;
    float4 p0 = *(const float4*)(px);
    float4 p1 = *(const float4*)(px + 4);
    float4 a0 = *(const float4*)(px + DDIM);
    float4 a1 = *(const float4*)(px + DDIM + 4);

    u16x8 pv, av;
    pv[0] = f2bf(p0.x); pv[1] = f2bf(p0.y); pv[2] = f2bf(p0.z); pv[3] = f2bf(p0.w);
    pv[4] = f2bf(p1.x); pv[5] = f2bf(p1.y); pv[6] = f2bf(p1.z); pv[7] = f2bf(p1.w);
    av[0] = f2bf(a0.x); av[1] = f2bf(a0.y); av[2] = f2bf(a0.z); av[3] = f2bf(a0.w);
    av[4] = f2bf(a1.x); av[5] = f2bf(a1.y); av[6] = f2bf(a1.z); av[7] = f2bf(a1.w);

    *(u16x8*)(Pf + (size_t)cid * 8) = pv;
    *(u16x8*)(Af + (size_t)cid * 8) = av;
}

// ---- MFMA GEMM + argmax + fused finalize, 128x128/wave, 4 waves ----
// 256x256 block tile, 4 waves (2m x 2n) of 128x128. Grid 256, XCD-swizzled.
// LDS per buffer (64KB, u32): P chunk(kh_l,fb) at kh_l*2048 + fb*256
// (fb 0..7 = 256 rows); A at +8192. Two buffers (t&1)*16384. BK=64.
// Wave w (0..3) stages fb = w and w+4 for both P and A: 16 loads/tile.
__global__ __launch_bounds__(256, 1) void mfma_gemm_argmax(const unsigned short* __restrict__ Pf,
                                                           const unsigned short* __restrict__ Af,
                                                           const float* __restrict__ inv_an,
                                                           u64* __restrict__ packed,
                                                           unsigned int* __restrict__ done,
                                                           float* __restrict__ out) {
    __shared__ __align__(16) unsigned int lds[32768];  // 128 KB, 2 x 64KB
    __shared__ unsigned int lastflag;
    __shared__ int cnt[4];

    const int bid = blockIdx.x;
    const int xcd = bid & 7;
    const int slt = bid >> 3;                       // 0..31
    const int rblk = (xcd >> 1) * 4 + (slt >> 3);   // 0..15
    const int cblk = (xcd & 1) * 8 + (slt & 7);     // 0..15
    const int r0 = rblk * 256;
    const int c0 = cblk * 256;

    const int wave = threadIdx.x >> 6;  // 0..3
    const int lane = threadIdx.x & 63;
    const int l31 = lane & 31;
    const int lh = lane >> 5;
    const int wm = wave & 1;   // m-half: rows wm*128..+127
    const int wn = wave >> 1;  // n-half: cols wn*128..+127

    // per-wave global stage pointers: wave stages fb = wave and wave+4
    const char* gP0 = (const char*)Pf + (((size_t)(rblk * 8 + wave)) << 16) + (size_t)lane * 16;
    const char* gP1 = (const char*)Pf + (((size_t)(rblk * 8 + wave + 4)) << 16) + (size_t)lane * 16;
    const char* gA0 = (const char*)Af + (((size_t)(cblk * 8 + wave)) << 16) + (size_t)lane * 16;
    const char* gA1 = (const char*)Af + (((size_t)(cblk * 8 + wave + 4)) << 16) + (size_t)lane * 16;

    f32x16 zero16 = {0.f,0.f,0.f,0.f,0.f,0.f,0.f,0.f,0.f,0.f,0.f,0.f,0.f,0.f,0.f,0.f};
    f32x16 acc[4][4];
#pragma unroll
    for (int i = 0; i < 4; ++i)
#pragma unroll
        for (int j = 0; j < 4; ++j) acc[i][j] = zero16;

    // two rotating frag sets (static indices -> registers)
    bf16x8 ph[2][4], aa[2][4];

    // stage tile tt (BK=64: kh = tt*4 .. +3) into buffer at u32 base bb
#define ISSUE_TILE(tt, bb)                                                              \
    {                                                                                   \
        _Pragma("unroll")                                                               \
        for (int kh_l = 0; kh_l < 4; ++kh_l) {                                          \
            const size_t go_ = ((size_t)((tt) * 4 + kh_l)) << 10;                       \
            __builtin_amdgcn_global_load_lds((const u32*)(gP0 + go_),                   \
                &lds[(bb) + kh_l * 2048 + wave * 256], 16, 0, 0);                       \
            __builtin_amdgcn_global_load_lds((const u32*)(gP1 + go_),                   \
                &lds[(bb) + kh_l * 2048 + (wave + 4) * 256], 16, 0, 0);                 \
            __builtin_amdgcn_global_load_lds((const u32*)(gA0 + go_),                   \
                &lds[(bb) + 8192 + kh_l * 2048 + wave * 256], 16, 0, 0);                \
            __builtin_amdgcn_global_load_lds((const u32*)(gA1 + go_),                   \
                &lds[(bb) + 8192 + kh_l * 2048 + (wave + 4) * 256], 16, 0, 0);          \
        }                                                                               \
    }

    // 8 ds_read: 4 P frags (rows wm*128, fb wm*4+i) + 4 A frags
#define READF(s, khl)                                                                   \
    {                                                                                   \
        const u32* bp_ = &lds[cbuf + (khl) * 2048 + (wm * 4) * 256 + lane * 4];         \
        ph[s][0] = *(const bf16x8*)(bp_);                                               \
        ph[s][1] = *(const bf16x8*)(bp_ + 256);                                         \
        ph[s][2] = *(const bf16x8*)(bp_ + 512);                                         \
        ph[s][3] = *(const bf16x8*)(bp_ + 768);                                         \
        const u32* ba_ = &lds[cbuf + 8192 + (khl) * 2048 + (wn * 4) * 256 + lane * 4];  \
        aa[s][0] = *(const bf16x8*)(ba_);                                               \
        aa[s][1] = *(const bf16x8*)(ba_ + 256);                                         \
        aa[s][2] = *(const bf16x8*)(ba_ + 512);                                         \
        aa[s][3] = *(const bf16x8*)(ba_ + 768);                                         \
    }

#define MFMA16(s)                                                                       \
    {                                                                                   \
        _Pragma("unroll")                                                               \
        for (int i = 0; i < 4; ++i) {                                                   \
            acc[i][0] = __builtin_amdgcn_mfma_f32_32x32x16_bf16(ph[s][i], aa[s][0], acc[i][0], 0, 0, 0); \
            acc[i][1] = __builtin_amdgcn_mfma_f32_32x32x16_bf16(ph[s][i], aa[s][1], acc[i][1], 0, 0, 0); \
            acc[i][2] = __builtin_amdgcn_mfma_f32_32x32x16_bf16(ph[s][i], aa[s][2], acc[i][2], 0, 0, 0); \
            acc[i][3] = __builtin_amdgcn_mfma_f32_32x32x16_bf16(ph[s][i], aa[s][3], acc[i][3], 0, 0, 0); \
        }                                                                               \
    }

    // ---- prologue: stage tile 0 into buffer 0 ----
    ISSUE_TILE(0, 0)

    // ---- K loop: 16 tiles of BK=64, 1 barrier/tile, pipelined reads ----
    for (int t = 0; t < 16; ++t) {
        const int cbuf = (t & 1) * 16384;
        const int nbuf = cbuf ^ 16384;

        // my 16 loads for tile t were issued one full tile ago -> drain
        asm volatile("s_waitcnt vmcnt(0)" ::: "memory");
        __builtin_amdgcn_s_barrier();   // tile t landed; all done reading nbuf
        __builtin_amdgcn_sched_barrier(0);

        if (t + 1 < 16) ISSUE_TILE(t + 1, nbuf)

        READF(0, 0)
#pragma unroll
        for (int kh = 0; kh < 4; ++kh) {
            if (kh < 3) READF((kh + 1) & 1, kh + 1)
            // current set's 8 reads done; next set's 8 may be outstanding
            if (kh < 3) { asm volatile("s_waitcnt lgkmcnt(8)" ::: "memory"); }
            else        { asm volatile("s_waitcnt lgkmcnt(0)" ::: "memory"); }
            __builtin_amdgcn_sched_barrier(0);   // rule #18
            __builtin_amdgcn_s_setprio(1);
            MFMA16(kh & 1)
            __builtin_amdgcn_s_setprio(0);
        }
    }
#undef ISSUE_TILE
#undef READF
#undef MFMA16

    // ---- epilogue: scale by inv_an, packed argmax ----
    float ian[4];
#pragma unroll
    for (int nt = 0; nt < 4; ++nt) ian[nt] = inv_an[c0 + wn * 128 + nt * 32 + l31];

    // 32x32 C/D layout (m74/m101): col = lane&31, row = (reg&3)+8*(reg>>2)+4*(lane>>5)
#pragma unroll
    for (int mt = 0; mt < 4; ++mt)
#pragma unroll
        for (int reg = 0; reg < 16; ++reg) {
            const int row = r0 + wm * 128 + mt * 32 + (reg & 3) + 8 * (reg >> 2) + 4 * lh;
            u64 best = 0ULL;
#pragma unroll
            for (int nt = 0; nt < 4; ++nt) {
                const int col = c0 + wn * 128 + nt * 32 + l31;
                const float v = acc[mt][nt][reg] * ian[nt];
                const u64 p = ((u64)fkey(v) << 32) | (unsigned int)(~col);
                best = best > p ? best : p;
            }
#pragma unroll
            for (int m = 1; m <= 16; m <<= 1) {
                const u64 o = shfl_xor_u64(best, m);
                best = best > o ? best : o;
            }
            if (l31 == 0) atomicMax(&packed[row], best);
        }

    // ---- fused finalize: last block counts and writes out ----
    __syncthreads();
    if (threadIdx.x == 0) {
        __threadfence();  // publish this block's atomicMax results
        unsigned int old = atomicAdd(done, 1u);
        lastflag = (old == 255u) ? 1u : 0u;
    }
    __syncthreads();
    if (lastflag) {
        int c = 0;
        for (int r = threadIdx.x; r < NROWS; r += 256) {
            u64 v = atomicAdd(&packed[r], 0ULL);  // device-coherent read
            unsigned int col = ~(unsigned int)(v & 0xFFFFFFFFULL);
            c += (col == (unsigned int)r) ? 1 : 0;
        }
#pragma unroll
        for (int off = 32; off > 0; off >>= 1) c += __shfl_down(c, off, 64);
        if ((threadIdx.x & 63) == 0) cnt[threadIdx.x >> 6] = c;
        __syncthreads();
        if (threadIdx.x == 0) {
            int tot = 0;
#pragma unroll
            for (int w = 0; w < 4; ++w) tot += cnt[w];
            out[0] = 1.0f;  // exp(temploss - stop_gradient(temploss)) == 1 exactly
            out[1] = 100.0f * (float)tot / (float)NROWS;
        }
    }
}

// ---------------- fallback fp32 path (proven R1) ----------------
__global__ __launch_bounds__(256) void norms_kernel(const float* __restrict__ x,
                                                    float* __restrict__ inv_an,
                                                    u64* __restrict__ packed) {
    int gid  = blockIdx.x * 256 + threadIdx.x;
    int j    = gid >> 6;
    int lane = threadIdx.x & 63;
    if (gid < NROWS) packed[gid] = 0ULL;
    const float4* a = (const float4*)(x + (size_t)j * XSTR + DDIM);
    float s = 0.0f;
#pragma unroll
    for (int i = 0; i < 4; ++i) {
        float4 v = a[lane + i * 64];
        s += v.x * v.x + v.y * v.y + v.z * v.z + v.w * v.w;
    }
#pragma unroll
    for (int off = 32; off > 0; off >>= 1) s += __shfl_down(s, off, 64);
    if (lane == 0) inv_an[j] = 1.0f / sqrtf(s);
}

__global__ __launch_bounds__(256) void gemm_argmax_kernel(const float* __restrict__ x,
                                                          const float* __restrict__ inv_an,
                                                          u64* __restrict__ packed) {
    __shared__ __align__(16) float Pt[16][128];
    __shared__ __align__(16) float At[16][128];
    const int r0 = blockIdx.x * 128;
    const int c0 = blockIdx.y * 128;
    const int t = threadIdx.x;
    const int tx = t & 15;
    const int ty = t >> 4;
    const int srow = t >> 1;
    const int skq = (t & 1) * 8;
    float acc[8][8];
#pragma unroll
    for (int r = 0; r < 8; ++r)
#pragma unroll
        for (int c = 0; c < 8; ++c) acc[r][c] = 0.0f;
    const float* gp = x + (size_t)(r0 + srow) * XSTR + skq;
    const float* ga = x + (size_t)(c0 + srow) * XSTR + DDIM + skq;
    for (int k0 = 0; k0 < DDIM; k0 += 16) {
        __syncthreads();
        float4 p0 = *(const float4*)(gp + k0);
        float4 p1 = *(const float4*)(gp + k0 + 4);
        float4 a0 = *(const float4*)(ga + k0);
        float4 a1 = *(const float4*)(ga + k0 + 4);
        Pt[skq + 0][srow] = p0.x; Pt[skq + 1][srow] = p0.y;
        Pt[skq + 2][srow] = p0.z; Pt[skq + 3][srow] = p0.w;
        Pt[skq + 4][srow] = p1.x; Pt[skq + 5][srow] = p1.y;
        Pt[skq + 6][srow] = p1.z; Pt[skq + 7][srow] = p1.w;
        At[skq + 0][srow] = a0.x; At[skq + 1][srow] = a0.y;
        At[skq + 2][srow] = a0.z; At[skq + 3][srow] = a0.w;
        At[skq + 4][srow] = a1.x; At[skq + 5][srow] = a1.y;
        At[skq + 6][srow] = a1.z; At[skq + 7][srow] = a1.w;
        __syncthreads();
#pragma unroll
        for (int kk = 0; kk < 16; ++kk) {
            float pr[8], ar[8];
            *(float4*)&pr[0] = *(const float4*)&Pt[kk][ty * 8];
            *(float4*)&pr[4] = *(const float4*)&Pt[kk][ty * 8 + 4];
            *(float4*)&ar[0] = *(const float4*)&At[kk][tx * 8];
            *(float4*)&ar[4] = *(const float4*)&At[kk][tx * 8 + 4];
#pragma unroll
            for (int r = 0; r < 8; ++r)
#pragma unroll
                for (int c = 0; c < 8; ++c) acc[r][c] += pr[r] * ar[c];
        }
    }
    float ian[8];
#pragma unroll
    for (int c = 0; c < 8; ++c) ian[c] = inv_an[c0 + tx * 8 + c];
#pragma unroll
    for (int r = 0; r < 8; ++r) {
        int row = r0 + ty * 8 + r;
        u64 best = 0ULL;
#pragma unroll
        for (int c = 0; c < 8; ++c) {
            int col = c0 + tx * 8 + c;
            float v = acc[r][c] * ian[c];
            u64 p = ((u64)fkey(v) << 32) | (unsigned int)(~col);
            best = best > p ? best : p;
        }
#pragma unroll
        for (int m = 1; m <= 8; m <<= 1) {
            u64 o = shfl_xor_u64(best, m);
            best = best > o ? best : o;
        }
        if (tx == 0) atomicMax(&packed[row], best);
    }
}

__global__ __launch_bounds__(256) void finalize_kernel(const u64* __restrict__ packed,
                                                       float* __restrict__ out) {
    __shared__ int cnt_s;
    int t = threadIdx.x;
    if (t == 0) cnt_s = 0;
    __syncthreads();
    int c = 0;
    for (int r = t; r < NROWS; r += 256) {
        unsigned int col = ~(unsigned int)(packed[r] & 0xFFFFFFFFULL);
        c += (col == (unsigned int)r) ? 1 : 0;
    }
#pragma unroll
    for (int off = 32; off > 0; off >>= 1) c += __shfl_down(c, off, 64);
    if ((t & 63) == 0) atomicAdd(&cnt_s, c);
    __syncthreads();
    if (t == 0) {
        out[0] = 1.0f;
        out[1] = 100.0f * (float)cnt_s / (float)NROWS;
    }
}

extern "C" void kernel_launch(void* const* d_in, const int* in_sizes, int n_in,
                              void* d_out, int out_size, void* d_ws, size_t ws_size,
                              hipStream_t stream) {
    (void)in_sizes; (void)n_in; (void)out_size;
    const float* x = (const float*)d_in[0];
    float* out = (float*)d_out;

    if (ws_size >= (size_t)WS_NEED) {
        char* ws = (char*)d_ws;
        unsigned short* Pf = (unsigned short*)(ws + PF_OFF);
        unsigned short* Af = (unsigned short*)(ws + AF_OFF);
        float* inv_an = (float*)(ws + INV_OFF);
        u64* packed = (u64*)(ws + PCK_OFF);
        unsigned int* done = (unsigned int*)(ws + DONE_OFF);

        norms2_kernel<<<NROWS / 4, 256, 0, stream>>>(x, inv_an, packed, done);
        conv_kernel<<<2048, 256, 0, stream>>>(x, Pf, Af);
        mfma_gemm_argmax<<<256, 256, 0, stream>>>(Pf, Af, inv_an, packed, done, out);
    } else {
        float* inv_an = (float*)d_ws;
        u64* packed = (u64*)((char*)d_ws + NROWS * sizeof(float));
        norms_kernel<<<NROWS / 4, 256, 0, stream>>>(x, inv_an, packed);
        dim3 grid(NROWS / 128, NROWS / 128);
        gemm_argmax_kernel<<<grid, 256, 0, stream>>>(x, inv_an, packed);
        finalize_kernel<<<1, 256, 0, stream>>>(packed, out);
    }
}

// Round 11
// 122.177 us; speedup vs baseline: 1.1281x; 1.1281x over previous
//
#include <hip/hip_runtime.h>

// x (4096, 2, 1024) fp32.  P_i = x[i,0,:], A_j = x[i,1,:]
// out[0] = 1.0 exactly; out[1] = prec1 = 100*mean(argmax_j sim[i,j] == i)
// argmax_j sim[i,j] == argmax_j dot(P_i,A_j)*inv_norm(A_j).
// R23: eight GEMM schedule variants (R12,R15,R17-R22) all land 22-27%
// MfmaUtil / 48.5-67.5us -> schedule space exhausted; GEMM reverted to the
// PROVEN fastest R15 (48.5us, fine-barriered phases, byte-identical).
// This round's change is prep: norms2's 16MB A re-read folded into conv
// (deterministic per-block LDS reduce + one atomicAdd per row per block;
// 16 contributors/row), packed/done/sums zeroed by one hipMemsetAsync,
// inv-norm computed as 1/sqrtf(sum) in the GEMM epilogue. Ulp-level sum
// order change cannot flip an argmax that survives bf16 rounding.
// Frag-order map (R4/R9/R11-verified): block fb region = 64KB at fb*65536;
// byte = kh*1024 + lane*16 -> (row = fb*32 + (lane&31), k = kh*16+(lane>>5)*8..+8).

#define NROWS 4096
#define DDIM  1024
#define XSTR  2048

typedef unsigned int u32;
typedef unsigned long long u64;
typedef __attribute__((ext_vector_type(8))) short bf16x8;
typedef __attribute__((ext_vector_type(8))) unsigned short u16x8;
typedef __attribute__((ext_vector_type(16))) float f32x16;

__device__ __forceinline__ unsigned int fkey(float f) {
    unsigned int u = __float_as_uint(f);
    return (u & 0x80000000u) ? ~u : (u | 0x80000000u);
}

__device__ __forceinline__ u64 shfl_xor_u64(u64 v, int m) {
    unsigned int lo = (unsigned int)v;
    unsigned int hi = (unsigned int)(v >> 32);
    lo = __shfl_xor(lo, m, 64);
    hi = __shfl_xor(hi, m, 64);
    return ((u64)hi << 32) | lo;
}

__device__ __forceinline__ unsigned short f2bf(float f) {
    unsigned u = __float_as_uint(f);
    return (unsigned short)((u + 0x7FFFu + ((u >> 16) & 1u)) >> 16);
}

// Workspace layout (bytes):
#define PF_OFF   0u
#define AF_OFF   8388608u
#define SUM_OFF  16777216u   // 4096 f32 row sum-of-squares (memset to 0)
#define PCK_OFF  16793600u
#define DONE_OFF 16826368u
#define WS_NEED  16826432u
// memset region: [SUM_OFF, WS_NEED) = sums + packed + done
#define ZERO_BYTES (WS_NEED - SUM_OFF)

// ---- prep: fp32 -> bf16 fragment conversion + fused anchor norm sums ----
// One thread per 16B chunk: cid = fb*4096 + kh*64 + lane (proven bit-exact
// frag output). Each thread also squares its 8 A-cols; deterministic block
// reduce (R12's rsum pattern) then one atomicAdd per row per block.
__global__ __launch_bounds__(256) void conv_kernel(const float* __restrict__ x,
                                                   unsigned short* __restrict__ Pf,
                                                   unsigned short* __restrict__ Af,
                                                   float* __restrict__ sums) {
    __shared__ float rsum[256];
    const int t    = threadIdx.x;
    const int cid  = blockIdx.x * 256 + t;
    const int lane = cid & 63;
    const int kh   = (cid >> 6) & 63;
    const int fb   = cid >> 12;            // constant per block (16 blocks/fb)
    const int row  = fb * 32 + (lane & 31);
    const int col  = kh * 16 + (lane >> 5) * 8;

    const float* px = x + (size_t)row * XSTR + col;
    float4 p0 = *(const float4*)(px);
    float4 p1 = *(const float4*)(px + 4);
    float4 a0 = *(const float4*)(px + DDIM);
    float4 a1 = *(const float4*)(px + DDIM + 4);

    u16x8 pv, av;
    pv[0] = f2bf(p0.x); pv[1] = f2bf(p0.y); pv[2] = f2bf(p0.z); pv[3] = f2bf(p0.w);
    pv[4] = f2bf(p1.x); pv[5] = f2bf(p1.y); pv[6] = f2bf(p1.z); pv[7] = f2bf(p1.w);
    av[0] = f2bf(a0.x); av[1] = f2bf(a0.y); av[2] = f2bf(a0.z); av[3] = f2bf(a0.w);
    av[4] = f2bf(a1.x); av[5] = f2bf(a1.y); av[6] = f2bf(a1.z); av[7] = f2bf(a1.w);

    *(u16x8*)(Pf + (size_t)cid * 8) = pv;
    *(u16x8*)(Af + (size_t)cid * 8) = av;

    float s = a0.x * a0.x + a0.y * a0.y + a0.z * a0.z + a0.w * a0.w
            + a1.x * a1.x + a1.y * a1.y + a1.z * a1.z + a1.w * a1.w;
    rsum[t] = s;
    __syncthreads();
    if (t < 32) {
        float tot = 0.0f;
#pragma unroll
        for (int w = 0; w < 8; ++w) tot += rsum[t + 32 * w];
        atomicAdd(&sums[fb * 32 + t], tot);   // 16 blocks contribute per row
    }
}

// ---- MFMA GEMM + argmax + fused finalize (R15 structure, proven 48.5us) ----
// 256x256 block tile, 8 waves (4m x 2n) of 64x128. Grid 256, XCD-swizzled.
// LDS per buffer (64KB): [P: kh_l*8KB + fb_l*1KB] [A: +32KB, same]; x2 dbuf.
// Wave w stages fb_l=w for both P and A (2 gload_lds per phase).
__global__ __launch_bounds__(512, 2) void mfma_gemm_argmax(const unsigned short* __restrict__ Pf,
                                                           const unsigned short* __restrict__ Af,
                                                           const float* __restrict__ sums,
                                                           u64* __restrict__ packed,
                                                           unsigned int* __restrict__ done,
                                                           float* __restrict__ out) {
    __shared__ __align__(16) unsigned int lds[32768];  // 128 KB, 2 x 64KB buffers
    __shared__ unsigned int lastflag;
    __shared__ int cnt[8];

    const int bid = blockIdx.x;
    const int xcd = bid & 7;
    const int slt = bid >> 3;                       // 0..31
    const int rblk = (xcd >> 1) * 4 + (slt >> 3);   // 0..15
    const int cblk = (xcd & 1) * 8 + (slt & 7);     // 0..15
    const int r0 = rblk * 256;
    const int c0 = cblk * 256;

    const int wave = threadIdx.x >> 6;  // 0..7
    const int lane = threadIdx.x & 63;
    const int l31 = lane & 31;
    const int lh = lane >> 5;
    const int wm = wave & 3;   // m-quarter: rows wm*64..+63
    const int wn = wave >> 2;  // n-half:    cols wn*128..+127

    // per-wave global stage pointers: wave stages frag-block fb_l = wave
    const char* gPs = (const char*)Pf + (((size_t)(rblk * 8 + wave)) << 16) + (size_t)lane * 16;
    const char* gAs = (const char*)Af + (((size_t)(cblk * 8 + wave)) << 16) + (size_t)lane * 16;

    f32x16 zero16 = {0.f,0.f,0.f,0.f,0.f,0.f,0.f,0.f,0.f,0.f,0.f,0.f,0.f,0.f,0.f,0.f};
    f32x16 acc[2][4];
#pragma unroll
    for (int i = 0; i < 2; ++i)
#pragma unroll
        for (int j = 0; j < 4; ++j) acc[i][j] = zero16;

    // ---- prologue: stage tile 0 into buffer 0 (8 loads per wave) ----
#pragma unroll
    for (int kh_l = 0; kh_l < 4; ++kh_l) {
        __builtin_amdgcn_global_load_lds((const u32*)(gPs + ((size_t)kh_l << 10)),
                                         &lds[kh_l * 2048 + wave * 256], 16, 0, 0);
        __builtin_amdgcn_global_load_lds((const u32*)(gAs + ((size_t)kh_l << 10)),
                                         &lds[8192 + kh_l * 2048 + wave * 256], 16, 0, 0);
    }

    // ---- K loop: 16 tiles of BK=64 (4 kh phases each) ----
    for (int t = 0; t < 16; ++t) {
        const int cb = t & 1;
        const int nbuf = (cb ^ 1) * 16384;
        const int cbuf = cb * 16384;

        // tile-t data landed everywhere (my 8 loads issued one full tile ago)
        asm volatile("s_waitcnt vmcnt(0)" ::: "memory");
        __builtin_amdgcn_s_barrier();
        __builtin_amdgcn_sched_barrier(0);

#pragma unroll
        for (int kh_l = 0; kh_l < 4; ++kh_l) {
            // ds_read this phase's 6 fragments (linear, conflict-free)
            const u32* bp = &lds[cbuf + kh_l * 2048 + (wm * 2) * 256 + lane * 4];
            bf16x8 f_p0 = *(const bf16x8*)(bp);
            bf16x8 f_p1 = *(const bf16x8*)(bp + 256);
            const u32* ba = &lds[cbuf + 8192 + kh_l * 2048 + (wn * 4) * 256 + lane * 4];
            bf16x8 f_a0 = *(const bf16x8*)(ba);
            bf16x8 f_a1 = *(const bf16x8*)(ba + 256);
            bf16x8 f_a2 = *(const bf16x8*)(ba + 512);
            bf16x8 f_a3 = *(const bf16x8*)(ba + 768);

            // issue 2 stage loads of tile t+1 (land by next tile's vmcnt)
            if (t + 1 < 16) {
                const size_t go = ((size_t)((t + 1) * 4 + kh_l)) << 10;
                __builtin_amdgcn_global_load_lds((const u32*)(gPs + go),
                                                 &lds[nbuf + kh_l * 2048 + wave * 256], 16, 0, 0);
                __builtin_amdgcn_global_load_lds((const u32*)(gAs + go),
                                                 &lds[nbuf + 8192 + kh_l * 2048 + wave * 256], 16, 0, 0);
            }

            __builtin_amdgcn_s_barrier();
            asm volatile("s_waitcnt lgkmcnt(0)" ::: "memory");
            __builtin_amdgcn_sched_barrier(0);
            __builtin_amdgcn_s_setprio(1);
            acc[0][0] = __builtin_amdgcn_mfma_f32_32x32x16_bf16(f_p0, f_a0, acc[0][0], 0, 0, 0);
            acc[0][1] = __builtin_amdgcn_mfma_f32_32x32x16_bf16(f_p0, f_a1, acc[0][1], 0, 0, 0);
            acc[0][2] = __builtin_amdgcn_mfma_f32_32x32x16_bf16(f_p0, f_a2, acc[0][2], 0, 0, 0);
            acc[0][3] = __builtin_amdgcn_mfma_f32_32x32x16_bf16(f_p0, f_a3, acc[0][3], 0, 0, 0);
            acc[1][0] = __builtin_amdgcn_mfma_f32_32x32x16_bf16(f_p1, f_a0, acc[1][0], 0, 0, 0);
            acc[1][1] = __builtin_amdgcn_mfma_f32_32x32x16_bf16(f_p1, f_a1, acc[1][1], 0, 0, 0);
            acc[1][2] = __builtin_amdgcn_mfma_f32_32x32x16_bf16(f_p1, f_a2, acc[1][2], 0, 0, 0);
            acc[1][3] = __builtin_amdgcn_mfma_f32_32x32x16_bf16(f_p1, f_a3, acc[1][3], 0, 0, 0);
            __builtin_amdgcn_s_setprio(0);
            __builtin_amdgcn_s_barrier();
        }
    }

    // ---- epilogue: ian = 1/sqrt(sum), packed argmax ----
    float ian[4];
#pragma unroll
    for (int nt = 0; nt < 4; ++nt) ian[nt] = 1.0f / sqrtf(sums[c0 + wn * 128 + nt * 32 + l31]);

    // 32x32 C/D layout (m74/m101): col = lane&31, row = (reg&3)+8*(reg>>2)+4*(lane>>5)
#pragma unroll
    for (int mt = 0; mt < 2; ++mt)
#pragma unroll
        for (int reg = 0; reg < 16; ++reg) {
            const int row = r0 + wm * 64 + mt * 32 + (reg & 3) + 8 * (reg >> 2) + 4 * lh;
            u64 best = 0ULL;
#pragma unroll
            for (int nt = 0; nt < 4; ++nt) {
                const int col = c0 + wn * 128 + nt * 32 + l31;
                const float v = acc[mt][nt][reg] * ian[nt];
                const u64 p = ((u64)fkey(v) << 32) | (unsigned int)(~col);
                best = best > p ? best : p;
            }
#pragma unroll
            for (int m = 1; m <= 16; m <<= 1) {
                const u64 o = shfl_xor_u64(best, m);
                best = best > o ? best : o;
            }
            if (l31 == 0) atomicMax(&packed[row], best);
        }

    // ---- fused finalize: last block counts and writes out ----
    __syncthreads();
    if (threadIdx.x == 0) {
        __threadfence();  // publish this block's atomicMax results
        unsigned int old = atomicAdd(done, 1u);
        lastflag = (old == 255u) ? 1u : 0u;
    }
    __syncthreads();
    if (lastflag) {
        int c = 0;
        for (int r = threadIdx.x; r < NROWS; r += 512) {
            u64 v = atomicAdd(&packed[r], 0ULL);  // device-coherent read
            unsigned int col = ~(unsigned int)(v & 0xFFFFFFFFULL);
            c += (col == (unsigned int)r) ? 1 : 0;
        }
#pragma unroll
        for (int off = 32; off > 0; off >>= 1) c += __shfl_down(c, off, 64);
        if ((threadIdx.x & 63) == 0) cnt[threadIdx.x >> 6] = c;
        __syncthreads();
        if (threadIdx.x == 0) {
            int tot = 0;
#pragma unroll
            for (int w = 0; w < 8; ++w) tot += cnt[w];
            out[0] = 1.0f;  // exp(temploss - stop_gradient(temploss)) == 1 exactly
            out[1] = 100.0f * (float)tot / (float)NROWS;
        }
    }
}

// ---------------- fallback fp32 path (proven R1) ----------------
__global__ __launch_bounds__(256) void norms_kernel(const float* __restrict__ x,
                                                    float* __restrict__ inv_an,
                                                    u64* __restrict__ packed) {
    int gid  = blockIdx.x * 256 + threadIdx.x;
    int j    = gid >> 6;
    int lane = threadIdx.x & 63;
    if (gid < NROWS) packed[gid] = 0ULL;
    const float4* a = (const float4*)(x + (size_t)j * XSTR + DDIM);
    float s = 0.0f;
#pragma unroll
    for (int i = 0; i < 4; ++i) {
        float4 v = a[lane + i * 64];
        s += v.x * v.x + v.y * v.y + v.z * v.z + v.w * v.w;
    }
#pragma unroll
    for (int off = 32; off > 0; off >>= 1) s += __shfl_down(s, off, 64);
    if (lane == 0) inv_an[j] = 1.0f / sqrtf(s);
}

__global__ __launch_bounds__(256) void gemm_argmax_kernel(const float* __restrict__ x,
                                                          const float* __restrict__ inv_an,
                                                          u64* __restrict__ packed) {
    __shared__ __align__(16) float Pt[16][128];
    __shared__ __align__(16) float At[16][128];
    const int r0 = blockIdx.x * 128;
    const int c0 = blockIdx.y * 128;
    const int t = threadIdx.x;
    const int tx = t & 15;
    const int ty = t >> 4;
    const int srow = t >> 1;
    const int skq = (t & 1) * 8;
    float acc[8][8];
#pragma unroll
    for (int r = 0; r < 8; ++r)
#pragma unroll
        for (int c = 0; c < 8; ++c) acc[r][c] = 0.0f;
    const float* gp = x + (size_t)(r0 + srow) * XSTR + skq;
    const float* ga = x + (size_t)(c0 + srow) * XSTR + DDIM + skq;
    for (int k0 = 0; k0 < DDIM; k0 += 16) {
        __syncthreads();
        float4 p0 = *(const float4*)(gp + k0);
        float4 p1 = *(const float4*)(gp + k0 + 4);
        float4 a0 = *(const float4*)(ga + k0);
        float4 a1 = *(const float4*)(ga + k0 + 4);
        Pt[skq + 0][srow] = p0.x; Pt[skq + 1][srow] = p0.y;
        Pt[skq + 2][srow] = p0.z; Pt[skq + 3][srow] = p0.w;
        Pt[skq + 4][srow] = p1.x; Pt[skq + 5][srow] = p1.y;
        Pt[skq + 6][srow] = p1.z; Pt[skq + 7][srow] = p1.w;
        At[skq + 0][srow] = a0.x; At[skq + 1][srow] = a0.y;
        At[skq + 2][srow] = a0.z; At[skq + 3][srow] = a0.w;
        At[skq + 4][srow] = a1.x; At[skq + 5][srow] = a1.y;
        At[skq + 6][srow] = a1.z; At[skq + 7][srow] = a1.w;
        __syncthreads();
#pragma unroll
        for (int kk = 0; kk < 16; ++kk) {
            float pr[8], ar[8];
            *(float4*)&pr[0] = *(const float4*)&Pt[kk][ty * 8];
            *(float4*)&pr[4] = *(const float4*)&Pt[kk][ty * 8 + 4];
            *(float4*)&ar[0] = *(const float4*)&At[kk][tx * 8];
            *(float4*)&ar[4] = *(const float4*)&At[kk][tx * 8 + 4];
#pragma unroll
            for (int r = 0; r < 8; ++r)
#pragma unroll
                for (int c = 0; c < 8; ++c) acc[r][c] += pr[r] * ar[c];
        }
    }
    float ian[8];
#pragma unroll
    for (int c = 0; c < 8; ++c) ian[c] = inv_an[c0 + tx * 8 + c];
#pragma unroll
    for (int r = 0; r < 8; ++r) {
        int row = r0 + ty * 8 + r;
        u64 best = 0ULL;
#pragma unroll
        for (int c = 0; c < 8; ++c) {
            int col = c0 + tx * 8 + c;
            float v = acc[r][c] * ian[c];
            u64 p = ((u64)fkey(v) << 32) | (unsigned int)(~col);
            best = best > p ? best : p;
        }
#pragma unroll
        for (int m = 1; m <= 8; m <<= 1) {
            u64 o = shfl_xor_u64(best, m);
            best = best > o ? best : o;
        }
        if (tx == 0) atomicMax(&packed[row], best);
    }
}

__global__ __launch_bounds__(256) void finalize_kernel(const u64* __restrict__ packed,
                                                       float* __restrict__ out) {
    __shared__ int cnt_s;
    int t = threadIdx.x;
    if (t == 0) cnt_s = 0;
    __syncthreads();
    int c = 0;
    for (int r = t; r < NROWS; r += 256) {
        unsigned int col = ~(unsigned int)(packed[r] & 0xFFFFFFFFULL);
        c += (col == (unsigned int)r) ? 1 : 0;
    }
#pragma unroll
    for (int off = 32; off > 0; off >>= 1) c += __shfl_down(c, off, 64);
    if ((t & 63) == 0) atomicAdd(&cnt_s, c);
    __syncthreads();
    if (t == 0) {
        out[0] = 1.0f;
        out[1] = 100.0f * (float)cnt_s / (float)NROWS;
    }
}

extern "C" void kernel_launch(void* const* d_in, const int* in_sizes, int n_in,
                              void* d_out, int out_size, void* d_ws, size_t ws_size,
                              hipStream_t stream) {
    (void)in_sizes; (void)n_in; (void)out_size;
    const float* x = (const float*)d_in[0];
    float* out = (float*)d_out;

    if (ws_size >= (size_t)WS_NEED) {
        char* ws = (char*)d_ws;
        unsigned short* Pf = (unsigned short*)(ws + PF_OFF);
        unsigned short* Af = (unsigned short*)(ws + AF_OFF);
        float* sums = (float*)(ws + SUM_OFF);
        u64* packed = (u64*)(ws + PCK_OFF);
        unsigned int* done = (unsigned int*)(ws + DONE_OFF);

        hipMemsetAsync(ws + SUM_OFF, 0, (size_t)ZERO_BYTES, stream);
        conv_kernel<<<2048, 256, 0, stream>>>(x, Pf, Af, sums);
        mfma_gemm_argmax<<<256, 512, 0, stream>>>(Pf, Af, sums, packed, done, out);
    } else {
        float* inv_an = (float*)d_ws;
        u64* packed = (u64*)((char*)d_ws + NROWS * sizeof(float));
        norms_kernel<<<NROWS / 4, 256, 0, stream>>>(x, inv_an, packed);
        dim3 grid(NROWS / 128, NROWS / 128);
        gemm_argmax_kernel<<<grid, 256, 0, stream>>>(x, inv_an, packed);
        finalize_kernel<<<1, 256, 0, stream>>>(packed, out);
    }
}